// Round 6
// baseline (481.673 us; speedup 1.0000x reference)
//
#include <hip/hip_runtime.h>
#include <hip/hip_bf16.h>
#include <math.h>

// Problem constants
#define TT 2048
#define BB 2
#define DM 1024
#define NH 16
#define HD 64
#define KVD 16
#define BT (BB*TT)   // 4096 rows total
#define QP 256       // NH*KVD
#define NBLK 512     // grid size: 2 blocks/CU needed, 4/CU capacity (2x margin)

typedef short short8  __attribute__((ext_vector_type(8)));
typedef short short4v __attribute__((ext_vector_type(4)));
typedef float f32x4   __attribute__((ext_vector_type(4)));
typedef float f32x16  __attribute__((ext_vector_type(16)));

static __device__ __forceinline__ short f2bf(float f) {
    union { float f; unsigned u; } v; v.f = f;
    unsigned r = v.u + 0x7fffu + ((v.u >> 16) & 1u);   // round-to-nearest-even
    return (short)(r >> 16);
}
static __device__ __forceinline__ float bf2f(short s) {
    union { unsigned u; float f; } c;
    c.u = ((unsigned)(unsigned short)s) << 16;
    return c.f;
}

// Software grid barrier: generation-counted, self-resetting (cnt returns to 0
// each use). cnt/gen zeroed by hipMemsetAsync at launch start. Agent-scope
// release/acquire + __threadfence give cross-XCD L2 visibility.
static __device__ __forceinline__ void grid_barrier(unsigned* cnt, unsigned* gen) {
    __syncthreads();
    if (threadIdx.x == 0) {
        __threadfence();
        unsigned g = __hip_atomic_load(gen, __ATOMIC_RELAXED, __HIP_MEMORY_SCOPE_AGENT);
        unsigned a = __hip_atomic_fetch_add(cnt, 1u, __ATOMIC_ACQ_REL, __HIP_MEMORY_SCOPE_AGENT);
        if (a == NBLK - 1u) {
            __hip_atomic_store(cnt, 0u, __ATOMIC_RELAXED, __HIP_MEMORY_SCOPE_AGENT);
            __hip_atomic_store(gen, g + 1u, __ATOMIC_RELEASE, __HIP_MEMORY_SCOPE_AGENT);
        } else {
            while (__hip_atomic_load(gen, __ATOMIC_ACQUIRE, __HIP_MEMORY_SCOPE_AGENT) == g)
                __builtin_amdgcn_s_sleep(4);
        }
        __threadfence();
    }
    __syncthreads();
}

// Single persistent kernel, 4 phases separated by software grid barriers:
//  0: absorbed weights (Wqt=log2e/8*Wq@Wk^T, Wvot=Wv@Wo, bqp, bop_part) + x->bf16 + latent kvc
//  1: q' GEMM  q16 = x @ Wq' + bq'                     [BT][256] bf16
//  2: causal latent attention (32x32 swapped MFMA)  -> u_bf [BT][256] bf16
//  3: out = U @ Wvot + (bo + bv@Wo)
// 512 blocks x 256 thr; launch_bounds(256,4) caps VGPR at 128; static LDS 12.5KB
// -> >=4 blocks/CU capacity, only 2/CU needed: all blocks co-resident.
__global__ __launch_bounds__(256, 4) void mla_fused(
    const float* __restrict__ Wq, const float* __restrict__ Wk,
    const float* __restrict__ bq,
    const float* __restrict__ Wv, const float* __restrict__ Wo,
    const float* __restrict__ bv,
    const float* __restrict__ x,  const float* __restrict__ Wc,
    const float* __restrict__ bc, const float* __restrict__ bo,
    short* __restrict__ Wqt, float* __restrict__ bqp,
    short* __restrict__ Wvot, float* __restrict__ bop_part,
    short* __restrict__ x_bf, short* __restrict__ kvc16, short* __restrict__ kvcT,
    short* __restrict__ q16, short* __restrict__ u_bf, float* __restrict__ out,
    unsigned* bar)
{
    __shared__ __align__(16) char smem[12800];
    const int bid = blockIdx.x, tid = threadIdx.x;
    unsigned* cnt = bar;
    unsigned* gen = bar + 16;   // separate cache lines

    // ================= phase 0: prep =================
    // items: [0,512) Wqt (h x 32-row d-tile); [512,576) Wvot; [576,1600) x/kvc (4 rows each)
    for (int item = bid; item < 1600; item += NBLK) {
        if (item < 512) {
            // ---- Wqt + bqp ----
            const float SC = 0.18033688011112042f;  // log2(e)/8
            float (*wk)[64] = (float(*)[64])smem;            // 4096 B
            float (*wq)[65] = (float(*)[65])(smem + 4096);   // 8320 B
            int h = item >> 5, dt = item & 31;
            int d0 = dt * 32;
            for (int idx = tid; idx < 1024; idx += 256) {
                int j = idx >> 6, e = idx & 63;
                wk[j][e] = Wk[j*DM + h*HD + e];
            }
            #pragma unroll
            for (int i = 0; i < 8; ++i) {
                int idx = i*256 + tid;
                int r = idx >> 6, e = idx & 63;
                wq[r][e] = Wq[(d0 + r)*DM + h*HD + e];
            }
            __syncthreads();
            int r = tid & 31, j0 = (tid >> 5) * 2;
            float a0 = 0.f, a1 = 0.f;
            #pragma unroll 8
            for (int e = 0; e < 64; ++e) {
                float a = wq[r][e];
                a0 += a * wk[j0+0][e];
                a1 += a * wk[j0+1][e];
            }
            Wqt[(h*16 + j0+0)*DM + d0 + r] = f2bf(a0 * SC);
            Wqt[(h*16 + j0+1)*DM + d0 + r] = f2bf(a1 * SC);
            if (dt == 0 && tid < 16) {
                int j = tid;
                float acc = 0.f;
                #pragma unroll 8
                for (int e = 0; e < 64; ++e) acc += bq[h*HD + e] * wk[j][e];
                bqp[h*16 + j] = acc * SC;
            }
        } else if (item < 576) {
            // ---- Wvot + bop_part ----
            float (*wv)[64] = (float(*)[64])smem;            // 4096 B
            float* bvs = (float*)(smem + 4096);              // 256 B
            int hb = item - 512;
            int h = hb >> 2, nt = hb & 3;
            int n = nt*256 + tid;
            for (int idx = tid; idx < 1024; idx += 256) {
                int j = idx >> 6, e = idx & 63;
                wv[j][e] = Wv[j*DM + h*HD + e];
            }
            if (tid < 64) bvs[tid] = bv[h*HD + tid];
            __syncthreads();
            float acc[16];
            #pragma unroll
            for (int j = 0; j < 16; ++j) acc[j] = 0.f;
            float bacc = 0.f;
            #pragma unroll 4
            for (int e = 0; e < 64; ++e) {
                float wo = Wo[(h*HD + e)*DM + n];
                bacc += bvs[e] * wo;
                #pragma unroll
                for (int j = 0; j < 16; ++j) acc[j] += wv[j][e] * wo;
            }
            short8 o0, o1;
            #pragma unroll
            for (int j = 0; j < 8; ++j) { o0[j] = f2bf(acc[j]); o1[j] = f2bf(acc[j+8]); }
            *(short8*)(Wvot + n*QP + h*16)     = o0;
            *(short8*)(Wvot + n*QP + h*16 + 8) = o1;
            bop_part[h*DM + n] = bacc;
        } else {
            // ---- x -> bf16, kvc (x staged in LDS as bf16) ----
            short (*xs)[DM]       = (short(*)[DM])smem;                // 8192 B
            float (*part)[16][17] = (float(*)[16][17])(smem + 8192);   // 4352 B
            int t0 = (item - 576) * 4;
            #pragma unroll
            for (int i = 0; i < 4; ++i) {
                float4 xv = *(const float4*)(x + (t0+i)*DM + tid*4);
                short4v xb;
                xb[0]=f2bf(xv.x); xb[1]=f2bf(xv.y); xb[2]=f2bf(xv.z); xb[3]=f2bf(xv.w);
                *(short4v*)(x_bf + (t0+i)*DM + tid*4) = xb;
                *(short4v*)(&xs[i][tid*4]) = xb;
            }
            __syncthreads();
            int g = tid >> 4, n = tid & 15;
            float a0=0.f, a1=0.f, a2=0.f, a3=0.f;
            #pragma unroll 4
            for (int k = 0; k < 64; ++k) {
                float wc = Wc[(g*64 + k)*KVD + n];
                a0 += bf2f(xs[0][g*64+k])*wc; a1 += bf2f(xs[1][g*64+k])*wc;
                a2 += bf2f(xs[2][g*64+k])*wc; a3 += bf2f(xs[3][g*64+k])*wc;
            }
            part[0][g][n]=a0; part[1][g][n]=a1; part[2][g][n]=a2; part[3][g][n]=a3;
            __syncthreads();
            if (tid < 64) {
                int i = tid >> 4, nn = tid & 15;
                float s = bc[nn];
                #pragma unroll
                for (int gg = 0; gg < 16; ++gg) s += part[i][gg][nn];
                short v = f2bf(s);
                int t = t0 + i;
                kvc16[t*16 + nn] = v;
                int b = t >> 11, tl = t & (TT-1);
                kvcT[(b*32 + nn)*TT + tl]      = v;
                kvcT[(b*32 + 16 + nn)*TT + tl] = 0;   // zero pad rows 16..31
            }
        }
        __syncthreads();   // smem reuse safety across items
    }

    grid_barrier(cnt, gen);

    // ================= phase 1: q' GEMM =================
    for (int t = bid; t < 1024; t += NBLK) {
        int w = tid >> 6, lane = tid & 63;
        int l15 = lane & 15, g = lane >> 4;
        int m0 = (t >> 4)*64 + w*16;
        int nb = (t & 15)*16;
        f32x4 acc = {0.f,0.f,0.f,0.f};
        const short* arow = x_bf + (m0 + l15)*DM + 8*g;
        const short* brow = Wqt  + (nb + l15)*DM + 8*g;
        for (int k0 = 0; k0 < DM; k0 += 32) {
            short8 a = *(const short8*)(arow + k0);
            short8 b = *(const short8*)(brow + k0);
            acc = __builtin_amdgcn_mfma_f32_16x16x32_bf16(a, b, acc, 0, 0, 0);
        }
        int c = nb + l15;
        float bias = bqp[c];
        #pragma unroll
        for (int r = 0; r < 4; ++r) {
            int row = m0 + 4*g + r;
            q16[row*QP + c] = f2bf(acc[r] + bias);
        }
    }

    grid_barrier(cnt, gen);

    // ================= phase 2: attention =================
    {
        float (*ulds)[32][17] = (float(*)[32][17])smem;      // 8704 B
        float (*dlds)[32]     = (float(*)[32])(smem + 8704); // 512 B
        int bh = bid & 31, pp = bid >> 5;      // pp in [0,16)
        int b = bh >> 4, h = bh & 15;
        int w = tid >> 6, lane = tid & 63;
        int l31 = lane & 31, hi = lane >> 5;

        // two complementary pairs: {pp, 63-pp} and {31-pp, 32+pp} -> 130 KV-tiles/block
        #pragma unroll 1
        for (int it = 0; it < 4; ++it) {
            int qt;
            switch (it) {
                case 0: qt = pp; break;
                case 1: qt = 63 - pp; break;
                case 2: qt = 31 - pp; break;
                default: qt = 32 + pp; break;
            }
            int qbase = qt * 32;

            short8 qf = *(const short8*)(q16 + (b*TT + qbase + l31)*QP + h*16 + 8*hi);
            const short* kbase = kvc16 + (b*TT + l31)*16 + 8*hi;
            const short* vrow  = kvcT + (b*32 + l31)*TT + 8*hi;

            int ntiles = qt + 1;
            int t0 = (w * ntiles) >> 2;
            int t1 = ((w + 1) * ntiles) >> 2;

            f32x16 u;
            f32x16 zf;
            #pragma unroll
            for (int r = 0; r < 16; ++r) { u[r] = 0.f; zf[r] = 0.f; }
            float lacc = 0.f;

            if (t0 < t1) {
                int kv0 = t0 << 5;
                short8 kf  = *(const short8*)(kbase + kv0*16);
                short8 va  = *(const short8*)(vrow + kv0);
                short8 vb  = *(const short8*)(vrow + kv0 + 16);
                for (int kt = t0; kt < t1; ++kt) {
                    short8 kf_n = kf, va_n = va, vb_n = vb;
                    if (kt + 1 < t1) {                  // prefetch next tile
                        int kvn = (kt + 1) << 5;
                        kf_n = *(const short8*)(kbase + kvn*16);
                        va_n = *(const short8*)(vrow + kvn);
                        vb_n = *(const short8*)(vrow + kvn + 16);
                    }
                    f32x16 st = __builtin_amdgcn_mfma_f32_32x32x16_bf16(kf, qf, zf, 0, 0, 0);
                    if (kt == qt) {                      // diagonal tile: mask kv > q
                        #pragma unroll
                        for (int r = 0; r < 16; ++r) {
                            int kvl = (r & 3) + 8*(r >> 2) + 4*hi;
                            if (kvl > l31) st[r] = -INFINITY;
                        }
                    }
                    float p[16];
                    #pragma unroll
                    for (int r = 0; r < 16; ++r) { p[r] = exp2f(st[r]); lacc += p[r]; }
                    int wd[8];
                    #pragma unroll
                    for (int i = 0; i < 8; ++i) {
                        asm("v_cvt_pk_bf16_f32 %0, %1, %2" : "=v"(wd[i]) : "v"(p[2*i]), "v"(p[2*i+1]));
                    }
                    // cross-half redistribute via permlane32_swap
                    int c00 = wd[0], c02 = wd[2], c01 = wd[1], c03 = wd[3];
                    int c10 = wd[4], c12 = wd[6], c11 = wd[5], c13 = wd[7];
                    asm volatile("v_permlane32_swap_b32 %0, %1" : "+v"(c00), "+v"(c02));
                    asm volatile("v_permlane32_swap_b32 %0, %1" : "+v"(c01), "+v"(c03));
                    asm volatile("v_permlane32_swap_b32 %0, %1" : "+v"(c10), "+v"(c12));
                    asm volatile("v_permlane32_swap_b32 %0, %1" : "+v"(c11), "+v"(c13));
                    union { int i4[4]; short8 s8; } pa0, pa1;
                    pa0.i4[0]=c00; pa0.i4[1]=c01; pa0.i4[2]=c02; pa0.i4[3]=c03;
                    pa1.i4[0]=c10; pa1.i4[1]=c11; pa1.i4[2]=c12; pa1.i4[3]=c13;
                    u = __builtin_amdgcn_mfma_f32_32x32x16_bf16(pa0.s8, va, u, 0, 0, 0);
                    u = __builtin_amdgcn_mfma_f32_32x32x16_bf16(pa1.s8, vb, u, 0, 0, 0);
                    kf = kf_n; va = va_n; vb = vb_n;
                }
            }

            // combine: per-wave partials are additive (no-max softmax)
            lacc += __shfl_xor(lacc, 32, 64);
            #pragma unroll
            for (int r = 0; r < 16; ++r) {
                int q = (r & 3) + 8*(r >> 2) + 4*hi;
                if (l31 < 16) ulds[w][q][l31] = u[r];
            }
            if (hi == 0) dlds[w][l31] = lacc;
            __syncthreads();
            #pragma unroll
            for (int e = 0; e < 2; ++e) {
                int idx = tid*2 + e;
                int q = idx >> 4, lat = idx & 15;
                float us = ulds[0][q][lat] + ulds[1][q][lat] + ulds[2][q][lat] + ulds[3][q][lat];
                float dd = dlds[0][q] + dlds[1][q] + dlds[2][q] + dlds[3][q];
                u_bf[(b*TT + qbase + q)*QP + h*16 + lat] = f2bf(us / dd);
            }
            __syncthreads();   // ulds/dlds reuse safety before next item
        }
    }

    grid_barrier(cnt, gen);

    // ================= phase 3: output GEMM =================
    for (int t = bid; t < 1024; t += NBLK) {
        int w = tid >> 6, lane = tid & 63;
        int l15 = lane & 15, g = lane >> 4;
        int m0 = (t >> 4)*64 + w*16;
        int nb = (t & 15)*64;
        float* bs = (float*)smem;
        if (tid < 64) {
            int n = nb + tid;
            float s = bo[n];
            #pragma unroll
            for (int hh = 0; hh < 16; ++hh) s += bop_part[hh*DM + n];
            bs[tid] = s;
        }
        __syncthreads();
        f32x4 acc[4];
        #pragma unroll
        for (int nt = 0; nt < 4; ++nt) acc[nt] = (f32x4){0.f,0.f,0.f,0.f};
        const short* arow = u_bf + (m0 + l15)*QP + 8*g;
        for (int k0 = 0; k0 < QP; k0 += 32) {
            short8 a = *(const short8*)(arow + k0);
            #pragma unroll
            for (int nt = 0; nt < 4; ++nt) {
                short8 bfr = *(const short8*)(Wvot + (nb + nt*16 + l15)*QP + k0 + 8*g);
                acc[nt] = __builtin_amdgcn_mfma_f32_16x16x32_bf16(a, bfr, acc[nt], 0, 0, 0);
            }
        }
        #pragma unroll
        for (int nt = 0; nt < 4; ++nt) {
            int n = nb + nt*16 + l15;
            float bias = bs[nt*16 + l15];
            #pragma unroll
            for (int r = 0; r < 4; ++r)
                out[(m0 + 4*g + r)*DM + n] = acc[nt][r] + bias;
        }
        __syncthreads();   // bs reuse safety
    }
}

extern "C" void kernel_launch(void* const* d_in, const int* in_sizes, int n_in,
                              void* d_out, int out_size, void* d_ws, size_t ws_size,
                              hipStream_t stream) {
    const float* x  = (const float*)d_in[0];
    const float* Wc = (const float*)d_in[1];
    const float* bc = (const float*)d_in[2];
    const float* Wk = (const float*)d_in[3];
    // d_in[4] = bk: drops out of softmax (constant per row)
    const float* Wv = (const float*)d_in[5];
    const float* bv = (const float*)d_in[6];
    const float* Wq = (const float*)d_in[7];
    const float* bq = (const float*)d_in[8];
    const float* Wo = (const float*)d_in[9];
    const float* bo = (const float*)d_in[10];
    // d_in[11] = mask: causal, implemented directly
    float* out = (float*)d_out;

    char* ws = (char*)d_ws;                       // needs 16 MiB
    short* x_bf     = (short*)(ws);                              // 8 MiB
    short* Wqt      = (short*)(ws + (8u<<20));                   // 512 KiB
    short* Wvot     = (short*)(ws + (8u<<20) + (512u<<10));      // 512 KiB
    float* bqp      = (float*)(ws + (9u<<20));                   // 1 KiB
    float* bop_part = (float*)(ws + (9u<<20) + 8192);            // 64 KiB
    unsigned* bar   = (unsigned*)(ws + (9u<<20) + (128u<<10));   // 128 B barrier state
    short* kvc16    = (short*)(ws + (9u<<20) + (512u<<10));      // 128 KiB
    short* kvcT     = (short*)(ws + (9u<<20) + (768u<<10));      // 256 KiB [B][32][T]
    short* q16      = (short*)(ws + (10u<<20));                  // 2 MiB [BT][256]
    short* u_bf     = (short*)(ws + (14u<<20));                  // 2 MiB

    hipMemsetAsync(bar, 0, 128, stream);   // zero barrier state (ws is poisoned)
    hipLaunchKernelGGL(mla_fused, dim3(NBLK), dim3(256), 0, stream,
                       Wq, Wk, bq, Wv, Wo, bv, x, Wc, bc, bo,
                       Wqt, bqp, Wvot, bop_part, x_bf, kvc16, kvcT,
                       q16, u_bf, out, bar);
}

// Round 7
// 230.048 us; speedup vs baseline: 2.0938x; 2.0938x over previous
//
#include <hip/hip_runtime.h>
#include <hip/hip_bf16.h>
#include <math.h>

// Problem constants
#define TT 2048
#define BB 2
#define DM 1024
#define NH 16
#define HD 64
#define KVD 16
#define BT (BB*TT)   // 4096 rows total
#define QP 256       // NH*KVD
#define NBLK 512     // grid size: 2 blocks/CU needed, 4/CU capacity (2x margin)

typedef short short8  __attribute__((ext_vector_type(8)));
typedef short short4v __attribute__((ext_vector_type(4)));
typedef float f32x4   __attribute__((ext_vector_type(4)));
typedef float f32x16  __attribute__((ext_vector_type(16)));

static __device__ __forceinline__ short f2bf(float f) {
    union { float f; unsigned u; } v; v.f = f;
    unsigned r = v.u + 0x7fffu + ((v.u >> 16) & 1u);   // round-to-nearest-even
    return (short)(r >> 16);
}
static __device__ __forceinline__ float bf2f(short s) {
    union { unsigned u; float f; } c;
    c.u = ((unsigned)(unsigned short)s) << 16;
    return c.f;
}

// Software grid barrier, generation-counted, self-resetting.
// KEY FIX vs round 6: the spin polls gen with RELAXED loads (no cache-inv
// side effects); ONE acquire load after the spin gives cross-XCD visibility
// (synchronizes-with the releaser's RELEASE store). cnt and gen live 256B
// apart so the cnt RMW doesn't bounce the polled line.
static __device__ __forceinline__ void grid_barrier(unsigned* cnt, unsigned* gen) {
    __syncthreads();
    if (threadIdx.x == 0) {
        __threadfence();   // make this block's phase writes visible (device scope)
        unsigned g = __hip_atomic_load(gen, __ATOMIC_RELAXED, __HIP_MEMORY_SCOPE_AGENT);
        unsigned a = __hip_atomic_fetch_add(cnt, 1u, __ATOMIC_ACQ_REL, __HIP_MEMORY_SCOPE_AGENT);
        if (a == NBLK - 1u) {
            __hip_atomic_store(cnt, 0u, __ATOMIC_RELAXED, __HIP_MEMORY_SCOPE_AGENT);
            __hip_atomic_store(gen, g + 1u, __ATOMIC_RELEASE, __HIP_MEMORY_SCOPE_AGENT);
        } else {
            while (__hip_atomic_load(gen, __ATOMIC_RELAXED, __HIP_MEMORY_SCOPE_AGENT) == g)
                __builtin_amdgcn_s_sleep(16);
            // one-time acquire: pairs with the RELEASE store of gen
            (void)__hip_atomic_load(gen, __ATOMIC_ACQUIRE, __HIP_MEMORY_SCOPE_AGENT);
        }
        __threadfence();
    }
    __syncthreads();
}

// Single persistent kernel, 4 phases separated by software grid barriers:
//  0: absorbed weights (Wqt=log2e/8*Wq@Wk^T, Wvot=Wv@Wo, bqp, bop_part) + x->bf16 + latent kvc
//  1: q' GEMM  q16 = x @ Wq' + bq'                     [BT][256] bf16
//  2: causal latent attention (32x32 swapped MFMA)  -> u_bf [BT][256] bf16
//  3: out = U @ Wvot + (bo + bv@Wo)
// 512 blocks x 256 thr; launch_bounds(256,4) caps VGPR at 128; static LDS 12.5KB
// -> >=4 blocks/CU capacity, only 2/CU needed: all blocks co-resident.
__global__ __launch_bounds__(256, 4) void mla_fused(
    const float* __restrict__ Wq, const float* __restrict__ Wk,
    const float* __restrict__ bq,
    const float* __restrict__ Wv, const float* __restrict__ Wo,
    const float* __restrict__ bv,
    const float* __restrict__ x,  const float* __restrict__ Wc,
    const float* __restrict__ bc, const float* __restrict__ bo,
    short* __restrict__ Wqt, float* __restrict__ bqp,
    short* __restrict__ Wvot, float* __restrict__ bop_part,
    short* __restrict__ x_bf, short* __restrict__ kvc16, short* __restrict__ kvcT,
    short* __restrict__ q16, short* __restrict__ u_bf, float* __restrict__ out,
    unsigned* bar)
{
    __shared__ __align__(16) char smem[12800];
    const int bid = blockIdx.x, tid = threadIdx.x;
    unsigned* cnt = bar;
    unsigned* gen = bar + 64;   // 256 B apart: separate L2 lines

    // ================= phase 0: prep =================
    // items: [0,512) Wqt (h x 32-row d-tile); [512,576) Wvot; [576,1600) x/kvc (4 rows each)
    for (int item = bid; item < 1600; item += NBLK) {
        if (item < 512) {
            // ---- Wqt + bqp ----
            const float SC = 0.18033688011112042f;  // log2(e)/8
            float (*wk)[64] = (float(*)[64])smem;            // 4096 B
            float (*wq)[65] = (float(*)[65])(smem + 4096);   // 8320 B
            int h = item >> 5, dt = item & 31;
            int d0 = dt * 32;
            for (int idx = tid; idx < 1024; idx += 256) {
                int j = idx >> 6, e = idx & 63;
                wk[j][e] = Wk[j*DM + h*HD + e];
            }
            #pragma unroll
            for (int i = 0; i < 8; ++i) {
                int idx = i*256 + tid;
                int r = idx >> 6, e = idx & 63;
                wq[r][e] = Wq[(d0 + r)*DM + h*HD + e];
            }
            __syncthreads();
            int r = tid & 31, j0 = (tid >> 5) * 2;
            float a0 = 0.f, a1 = 0.f;
            #pragma unroll 8
            for (int e = 0; e < 64; ++e) {
                float a = wq[r][e];
                a0 += a * wk[j0+0][e];
                a1 += a * wk[j0+1][e];
            }
            Wqt[(h*16 + j0+0)*DM + d0 + r] = f2bf(a0 * SC);
            Wqt[(h*16 + j0+1)*DM + d0 + r] = f2bf(a1 * SC);
            if (dt == 0 && tid < 16) {
                int j = tid;
                float acc = 0.f;
                #pragma unroll 8
                for (int e = 0; e < 64; ++e) acc += bq[h*HD + e] * wk[j][e];
                bqp[h*16 + j] = acc * SC;
            }
        } else if (item < 576) {
            // ---- Wvot + bop_part ----
            float (*wv)[64] = (float(*)[64])smem;            // 4096 B
            float* bvs = (float*)(smem + 4096);              // 256 B
            int hb = item - 512;
            int h = hb >> 2, nt = hb & 3;
            int n = nt*256 + tid;
            for (int idx = tid; idx < 1024; idx += 256) {
                int j = idx >> 6, e = idx & 63;
                wv[j][e] = Wv[j*DM + h*HD + e];
            }
            if (tid < 64) bvs[tid] = bv[h*HD + tid];
            __syncthreads();
            float acc[16];
            #pragma unroll
            for (int j = 0; j < 16; ++j) acc[j] = 0.f;
            float bacc = 0.f;
            #pragma unroll 4
            for (int e = 0; e < 64; ++e) {
                float wo = Wo[(h*HD + e)*DM + n];
                bacc += bvs[e] * wo;
                #pragma unroll
                for (int j = 0; j < 16; ++j) acc[j] += wv[j][e] * wo;
            }
            short8 o0, o1;
            #pragma unroll
            for (int j = 0; j < 8; ++j) { o0[j] = f2bf(acc[j]); o1[j] = f2bf(acc[j+8]); }
            *(short8*)(Wvot + n*QP + h*16)     = o0;
            *(short8*)(Wvot + n*QP + h*16 + 8) = o1;
            bop_part[h*DM + n] = bacc;
        } else {
            // ---- x -> bf16, kvc (x staged in LDS as bf16) ----
            short (*xs)[DM]       = (short(*)[DM])smem;                // 8192 B
            float (*part)[16][17] = (float(*)[16][17])(smem + 8192);   // 4352 B
            int t0 = (item - 576) * 4;
            #pragma unroll
            for (int i = 0; i < 4; ++i) {
                float4 xv = *(const float4*)(x + (t0+i)*DM + tid*4);
                short4v xb;
                xb[0]=f2bf(xv.x); xb[1]=f2bf(xv.y); xb[2]=f2bf(xv.z); xb[3]=f2bf(xv.w);
                *(short4v*)(x_bf + (t0+i)*DM + tid*4) = xb;
                *(short4v*)(&xs[i][tid*4]) = xb;
            }
            __syncthreads();
            int g = tid >> 4, n = tid & 15;
            float a0=0.f, a1=0.f, a2=0.f, a3=0.f;
            #pragma unroll 4
            for (int k = 0; k < 64; ++k) {
                float wc = Wc[(g*64 + k)*KVD + n];
                a0 += bf2f(xs[0][g*64+k])*wc; a1 += bf2f(xs[1][g*64+k])*wc;
                a2 += bf2f(xs[2][g*64+k])*wc; a3 += bf2f(xs[3][g*64+k])*wc;
            }
            part[0][g][n]=a0; part[1][g][n]=a1; part[2][g][n]=a2; part[3][g][n]=a3;
            __syncthreads();
            if (tid < 64) {
                int i = tid >> 4, nn = tid & 15;
                float s = bc[nn];
                #pragma unroll
                for (int gg = 0; gg < 16; ++gg) s += part[i][gg][nn];
                short v = f2bf(s);
                int t = t0 + i;
                kvc16[t*16 + nn] = v;
                int b = t >> 11, tl = t & (TT-1);
                kvcT[(b*32 + nn)*TT + tl]      = v;
                kvcT[(b*32 + 16 + nn)*TT + tl] = 0;   // zero pad rows 16..31
            }
        }
        __syncthreads();   // smem reuse safety across items
    }

    grid_barrier(cnt, gen);

    // ================= phase 1: q' GEMM =================
    for (int t = bid; t < 1024; t += NBLK) {
        int w = tid >> 6, lane = tid & 63;
        int l15 = lane & 15, g = lane >> 4;
        int m0 = (t >> 4)*64 + w*16;
        int nb = (t & 15)*16;
        f32x4 acc = {0.f,0.f,0.f,0.f};
        const short* arow = x_bf + (m0 + l15)*DM + 8*g;
        const short* brow = Wqt  + (nb + l15)*DM + 8*g;
        for (int k0 = 0; k0 < DM; k0 += 32) {
            short8 a = *(const short8*)(arow + k0);
            short8 b = *(const short8*)(brow + k0);
            acc = __builtin_amdgcn_mfma_f32_16x16x32_bf16(a, b, acc, 0, 0, 0);
        }
        int c = nb + l15;
        float bias = bqp[c];
        #pragma unroll
        for (int r = 0; r < 4; ++r) {
            int row = m0 + 4*g + r;
            q16[row*QP + c] = f2bf(acc[r] + bias);
        }
    }

    grid_barrier(cnt, gen);

    // ================= phase 2: attention =================
    {
        float (*ulds)[32][17] = (float(*)[32][17])smem;      // 8704 B
        float (*dlds)[32]     = (float(*)[32])(smem + 8704); // 512 B
        int bh = bid & 31, pp = bid >> 5;      // pp in [0,16)
        int b = bh >> 4, h = bh & 15;
        int w = tid >> 6, lane = tid & 63;
        int l31 = lane & 31, hi = lane >> 5;

        // two complementary pairs: {pp, 63-pp} and {31-pp, 32+pp} -> 130 KV-tiles/block
        #pragma unroll 1
        for (int it = 0; it < 4; ++it) {
            int qt;
            switch (it) {
                case 0: qt = pp; break;
                case 1: qt = 63 - pp; break;
                case 2: qt = 31 - pp; break;
                default: qt = 32 + pp; break;
            }
            int qbase = qt * 32;

            short8 qf = *(const short8*)(q16 + (b*TT + qbase + l31)*QP + h*16 + 8*hi);
            const short* kbase = kvc16 + (b*TT + l31)*16 + 8*hi;
            const short* vrow  = kvcT + (b*32 + l31)*TT + 8*hi;

            int ntiles = qt + 1;
            int t0 = (w * ntiles) >> 2;
            int t1 = ((w + 1) * ntiles) >> 2;

            f32x16 u;
            f32x16 zf;
            #pragma unroll
            for (int r = 0; r < 16; ++r) { u[r] = 0.f; zf[r] = 0.f; }
            float lacc = 0.f;

            if (t0 < t1) {
                int kv0 = t0 << 5;
                short8 kf  = *(const short8*)(kbase + kv0*16);
                short8 va  = *(const short8*)(vrow + kv0);
                short8 vb  = *(const short8*)(vrow + kv0 + 16);
                for (int kt = t0; kt < t1; ++kt) {
                    short8 kf_n = kf, va_n = va, vb_n = vb;
                    if (kt + 1 < t1) {                  // prefetch next tile
                        int kvn = (kt + 1) << 5;
                        kf_n = *(const short8*)(kbase + kvn*16);
                        va_n = *(const short8*)(vrow + kvn);
                        vb_n = *(const short8*)(vrow + kvn + 16);
                    }
                    f32x16 st = __builtin_amdgcn_mfma_f32_32x32x16_bf16(kf, qf, zf, 0, 0, 0);
                    if (kt == qt) {                      // diagonal tile: mask kv > q
                        #pragma unroll
                        for (int r = 0; r < 16; ++r) {
                            int kvl = (r & 3) + 8*(r >> 2) + 4*hi;
                            if (kvl > l31) st[r] = -INFINITY;
                        }
                    }
                    float p[16];
                    #pragma unroll
                    for (int r = 0; r < 16; ++r) { p[r] = exp2f(st[r]); lacc += p[r]; }
                    int wd[8];
                    #pragma unroll
                    for (int i = 0; i < 8; ++i) {
                        asm("v_cvt_pk_bf16_f32 %0, %1, %2" : "=v"(wd[i]) : "v"(p[2*i]), "v"(p[2*i+1]));
                    }
                    // cross-half redistribute via permlane32_swap
                    int c00 = wd[0], c02 = wd[2], c01 = wd[1], c03 = wd[3];
                    int c10 = wd[4], c12 = wd[6], c11 = wd[5], c13 = wd[7];
                    asm volatile("v_permlane32_swap_b32 %0, %1" : "+v"(c00), "+v"(c02));
                    asm volatile("v_permlane32_swap_b32 %0, %1" : "+v"(c01), "+v"(c03));
                    asm volatile("v_permlane32_swap_b32 %0, %1" : "+v"(c10), "+v"(c12));
                    asm volatile("v_permlane32_swap_b32 %0, %1" : "+v"(c11), "+v"(c13));
                    union { int i4[4]; short8 s8; } pa0, pa1;
                    pa0.i4[0]=c00; pa0.i4[1]=c01; pa0.i4[2]=c02; pa0.i4[3]=c03;
                    pa1.i4[0]=c10; pa1.i4[1]=c11; pa1.i4[2]=c12; pa1.i4[3]=c13;
                    u = __builtin_amdgcn_mfma_f32_32x32x16_bf16(pa0.s8, va, u, 0, 0, 0);
                    u = __builtin_amdgcn_mfma_f32_32x32x16_bf16(pa1.s8, vb, u, 0, 0, 0);
                    kf = kf_n; va = va_n; vb = vb_n;
                }
            }

            // combine: per-wave partials are additive (no-max softmax)
            lacc += __shfl_xor(lacc, 32, 64);
            #pragma unroll
            for (int r = 0; r < 16; ++r) {
                int q = (r & 3) + 8*(r >> 2) + 4*hi;
                if (l31 < 16) ulds[w][q][l31] = u[r];
            }
            if (hi == 0) dlds[w][l31] = lacc;
            __syncthreads();
            #pragma unroll
            for (int e = 0; e < 2; ++e) {
                int idx = tid*2 + e;
                int q = idx >> 4, lat = idx & 15;
                float us = ulds[0][q][lat] + ulds[1][q][lat] + ulds[2][q][lat] + ulds[3][q][lat];
                float dd = dlds[0][q] + dlds[1][q] + dlds[2][q] + dlds[3][q];
                u_bf[(b*TT + qbase + q)*QP + h*16 + lat] = f2bf(us / dd);
            }
            __syncthreads();   // ulds/dlds reuse safety before next item
        }
    }

    grid_barrier(cnt, gen);

    // ================= phase 3: output GEMM =================
    for (int t = bid; t < 1024; t += NBLK) {
        int w = tid >> 6, lane = tid & 63;
        int l15 = lane & 15, g = lane >> 4;
        int m0 = (t >> 4)*64 + w*16;
        int nb = (t & 15)*64;
        float* bs = (float*)smem;
        if (tid < 64) {
            int n = nb + tid;
            float s = bo[n];
            #pragma unroll
            for (int hh = 0; hh < 16; ++hh) s += bop_part[hh*DM + n];
            bs[tid] = s;
        }
        __syncthreads();
        f32x4 acc[4];
        #pragma unroll
        for (int nt = 0; nt < 4; ++nt) acc[nt] = (f32x4){0.f,0.f,0.f,0.f};
        const short* arow = u_bf + (m0 + l15)*QP + 8*g;
        for (int k0 = 0; k0 < QP; k0 += 32) {
            short8 a = *(const short8*)(arow + k0);
            #pragma unroll
            for (int nt = 0; nt < 4; ++nt) {
                short8 bfr = *(const short8*)(Wvot + (nb + nt*16 + l15)*QP + k0 + 8*g);
                acc[nt] = __builtin_amdgcn_mfma_f32_16x16x32_bf16(a, bfr, acc[nt], 0, 0, 0);
            }
        }
        #pragma unroll
        for (int nt = 0; nt < 4; ++nt) {
            int n = nb + nt*16 + l15;
            float bias = bs[nt*16 + l15];
            #pragma unroll
            for (int r = 0; r < 4; ++r)
                out[(m0 + 4*g + r)*DM + n] = acc[nt][r] + bias;
        }
        __syncthreads();   // bs reuse safety
    }
}

extern "C" void kernel_launch(void* const* d_in, const int* in_sizes, int n_in,
                              void* d_out, int out_size, void* d_ws, size_t ws_size,
                              hipStream_t stream) {
    const float* x  = (const float*)d_in[0];
    const float* Wc = (const float*)d_in[1];
    const float* bc = (const float*)d_in[2];
    const float* Wk = (const float*)d_in[3];
    // d_in[4] = bk: drops out of softmax (constant per row)
    const float* Wv = (const float*)d_in[5];
    const float* bv = (const float*)d_in[6];
    const float* Wq = (const float*)d_in[7];
    const float* bq = (const float*)d_in[8];
    const float* Wo = (const float*)d_in[9];
    const float* bo = (const float*)d_in[10];
    // d_in[11] = mask: causal, implemented directly
    float* out = (float*)d_out;

    char* ws = (char*)d_ws;                       // needs 16 MiB
    short* x_bf     = (short*)(ws);                              // 8 MiB
    short* Wqt      = (short*)(ws + (8u<<20));                   // 512 KiB
    short* Wvot     = (short*)(ws + (8u<<20) + (512u<<10));      // 512 KiB
    float* bqp      = (float*)(ws + (9u<<20));                   // 1 KiB
    float* bop_part = (float*)(ws + (9u<<20) + 8192);            // 64 KiB
    unsigned* bar   = (unsigned*)(ws + (9u<<20) + (128u<<10));   // 512 B barrier state
    short* kvc16    = (short*)(ws + (9u<<20) + (512u<<10));      // 128 KiB
    short* kvcT     = (short*)(ws + (9u<<20) + (768u<<10));      // 256 KiB [B][32][T]
    short* q16      = (short*)(ws + (10u<<20));                  // 2 MiB [BT][256]
    short* u_bf     = (short*)(ws + (14u<<20));                  // 2 MiB

    hipMemsetAsync(bar, 0, 512, stream);   // zero barrier state (ws is poisoned)
    hipLaunchKernelGGL(mla_fused, dim3(NBLK), dim3(256), 0, stream,
                       Wq, Wk, bq, Wv, Wo, bv, x, Wc, bc, bo,
                       Wqt, bqp, Wvot, bop_part, x_bf, kvc16, kvcT,
                       q16, u_bf, out, bar);
}

// Round 8
// 172.745 us; speedup vs baseline: 2.7883x; 1.3317x over previous
//
#include <hip/hip_runtime.h>
#include <hip/hip_bf16.h>
#include <math.h>

// Problem constants
#define TT 2048
#define BB 2
#define DM 1024
#define NH 16
#define HD 64
#define KVD 16
#define BT (BB*TT)   // 4096 rows total
#define QP 256       // NH*KVD
#define NBLK 512     // grid size: 2 blocks/CU needed, 4/CU capacity (2x margin)

typedef short short8  __attribute__((ext_vector_type(8)));
typedef short short4v __attribute__((ext_vector_type(4)));
typedef float f32x4   __attribute__((ext_vector_type(4)));
typedef float f32x16  __attribute__((ext_vector_type(16)));

static __device__ __forceinline__ short f2bf(float f) {
    union { float f; unsigned u; } v; v.f = f;
    unsigned r = v.u + 0x7fffu + ((v.u >> 16) & 1u);   // round-to-nearest-even
    return (short)(r >> 16);
}
static __device__ __forceinline__ float bf2f(short s) {
    union { unsigned u; float f; } c;
    c.u = ((unsigned)(unsigned short)s) << 16;
    return c.f;
}

// Flag-tree grid barrier (no contended RMW):
//  - each block release-stores generation g to its OWN flag word (no serialization)
//  - block 0's threads poll all flags in parallel (relaxed), __threadfence()
//    (acquire upgrade), then one release-store of gen
//  - other blocks poll gen relaxed + one final acquire load
// flags[] and gen zeroed by hipMemsetAsync each launch; generations 1,2,3.
static __device__ __forceinline__ void grid_barrier(unsigned* gen, unsigned* flags, unsigned g1) {
    __syncthreads();
    if (blockIdx.x == 0) {
        int tid = threadIdx.x;
        #pragma unroll 1
        for (int i = tid; i < NBLK; i += 256) {
            if (i != 0) {
                while (__hip_atomic_load(&flags[i], __ATOMIC_RELAXED, __HIP_MEMORY_SCOPE_AGENT) != g1)
                    __builtin_amdgcn_s_sleep(8);
            }
        }
        __threadfence();   // acquire-upgrade of relaxed polls + release of own phase writes
        __syncthreads();
        if (tid == 0)
            __hip_atomic_store(gen, g1, __ATOMIC_RELEASE, __HIP_MEMORY_SCOPE_AGENT);
    } else {
        if (threadIdx.x == 0) {
            __hip_atomic_store(&flags[blockIdx.x], g1, __ATOMIC_RELEASE, __HIP_MEMORY_SCOPE_AGENT);
            while (__hip_atomic_load(gen, __ATOMIC_RELAXED, __HIP_MEMORY_SCOPE_AGENT) != g1)
                __builtin_amdgcn_s_sleep(8);
            (void)__hip_atomic_load(gen, __ATOMIC_ACQUIRE, __HIP_MEMORY_SCOPE_AGENT);
        }
    }
    __syncthreads();
}

// Single persistent kernel, 4 phases separated by software grid barriers:
//  0: absorbed weights (Wqt=log2e/8*Wq@Wk^T, Wvot=Wv@Wo, bqp, bop_part) + x->bf16 + latent kvc
//  1: q' GEMM  q16 = x @ Wq' + bq'                     [BT][256] bf16
//  2: causal latent attention (32x32 swapped MFMA)  -> u_bf [BT][256] bf16
//  3: out = U @ Wvot + (bo + bv@Wo)
__global__ __launch_bounds__(256, 4) void mla_fused(
    const float* __restrict__ Wq, const float* __restrict__ Wk,
    const float* __restrict__ bq,
    const float* __restrict__ Wv, const float* __restrict__ Wo,
    const float* __restrict__ bv,
    const float* __restrict__ x,  const float* __restrict__ Wc,
    const float* __restrict__ bc, const float* __restrict__ bo,
    short* __restrict__ Wqt, float* __restrict__ bqp,
    short* __restrict__ Wvot, float* __restrict__ bop_part,
    short* __restrict__ x_bf, short* __restrict__ kvc16, short* __restrict__ kvcT,
    short* __restrict__ q16, short* __restrict__ u_bf, float* __restrict__ out,
    unsigned* bar)
{
    __shared__ __align__(16) char smem[12800];
    const int bid = blockIdx.x, tid = threadIdx.x;
    unsigned* gen   = bar;
    unsigned* flags = bar + 64;   // 256 B past gen; flags[1..511]

    // ================= phase 0: prep =================
    // items: [0,512) Wqt (h x 32-row d-tile); [512,576) Wvot; [576,1600) x/kvc (4 rows each)
    for (int item = bid; item < 1600; item += NBLK) {
        if (item < 512) {
            // ---- Wqt + bqp ----
            const float SC = 0.18033688011112042f;  // log2(e)/8
            float (*wk)[64] = (float(*)[64])smem;            // 4096 B
            float (*wq)[65] = (float(*)[65])(smem + 4096);   // 8320 B
            int h = item >> 5, dt = item & 31;
            int d0 = dt * 32;
            for (int idx = tid; idx < 1024; idx += 256) {
                int j = idx >> 6, e = idx & 63;
                wk[j][e] = Wk[j*DM + h*HD + e];
            }
            #pragma unroll
            for (int i = 0; i < 8; ++i) {
                int idx = i*256 + tid;
                int r = idx >> 6, e = idx & 63;
                wq[r][e] = Wq[(d0 + r)*DM + h*HD + e];
            }
            __syncthreads();
            int r = tid & 31, j0 = (tid >> 5) * 2;
            float a0 = 0.f, a1 = 0.f;
            #pragma unroll 8
            for (int e = 0; e < 64; ++e) {
                float a = wq[r][e];
                a0 += a * wk[j0+0][e];
                a1 += a * wk[j0+1][e];
            }
            Wqt[(h*16 + j0+0)*DM + d0 + r] = f2bf(a0 * SC);
            Wqt[(h*16 + j0+1)*DM + d0 + r] = f2bf(a1 * SC);
            if (dt == 0 && tid < 16) {
                int j = tid;
                float acc = 0.f;
                #pragma unroll 8
                for (int e = 0; e < 64; ++e) acc += bq[h*HD + e] * wk[j][e];
                bqp[h*16 + j] = acc * SC;
            }
        } else if (item < 576) {
            // ---- Wvot + bop_part ----
            float (*wv)[64] = (float(*)[64])smem;            // 4096 B
            float* bvs = (float*)(smem + 4096);              // 256 B
            int hb = item - 512;
            int h = hb >> 2, nt = hb & 3;
            int n = nt*256 + tid;
            for (int idx = tid; idx < 1024; idx += 256) {
                int j = idx >> 6, e = idx & 63;
                wv[j][e] = Wv[j*DM + h*HD + e];
            }
            if (tid < 64) bvs[tid] = bv[h*HD + tid];
            __syncthreads();
            float acc[16];
            #pragma unroll
            for (int j = 0; j < 16; ++j) acc[j] = 0.f;
            float bacc = 0.f;
            #pragma unroll 4
            for (int e = 0; e < 64; ++e) {
                float wo = Wo[(h*HD + e)*DM + n];
                bacc += bvs[e] * wo;
                #pragma unroll
                for (int j = 0; j < 16; ++j) acc[j] += wv[j][e] * wo;
            }
            short8 o0, o1;
            #pragma unroll
            for (int j = 0; j < 8; ++j) { o0[j] = f2bf(acc[j]); o1[j] = f2bf(acc[j+8]); }
            *(short8*)(Wvot + n*QP + h*16)     = o0;
            *(short8*)(Wvot + n*QP + h*16 + 8) = o1;
            bop_part[h*DM + n] = bacc;
        } else {
            // ---- x -> bf16, kvc (x staged in LDS as bf16) ----
            short (*xs)[DM]       = (short(*)[DM])smem;                // 8192 B
            float (*part)[16][17] = (float(*)[16][17])(smem + 8192);   // 4352 B
            int t0 = (item - 576) * 4;
            #pragma unroll
            for (int i = 0; i < 4; ++i) {
                float4 xv = *(const float4*)(x + (t0+i)*DM + tid*4);
                short4v xb;
                xb[0]=f2bf(xv.x); xb[1]=f2bf(xv.y); xb[2]=f2bf(xv.z); xb[3]=f2bf(xv.w);
                *(short4v*)(x_bf + (t0+i)*DM + tid*4) = xb;
                *(short4v*)(&xs[i][tid*4]) = xb;
            }
            __syncthreads();
            int g = tid >> 4, n = tid & 15;
            float a0=0.f, a1=0.f, a2=0.f, a3=0.f;
            #pragma unroll 4
            for (int k = 0; k < 64; ++k) {
                float wc = Wc[(g*64 + k)*KVD + n];
                a0 += bf2f(xs[0][g*64+k])*wc; a1 += bf2f(xs[1][g*64+k])*wc;
                a2 += bf2f(xs[2][g*64+k])*wc; a3 += bf2f(xs[3][g*64+k])*wc;
            }
            part[0][g][n]=a0; part[1][g][n]=a1; part[2][g][n]=a2; part[3][g][n]=a3;
            __syncthreads();
            if (tid < 64) {
                int i = tid >> 4, nn = tid & 15;
                float s = bc[nn];
                #pragma unroll
                for (int gg = 0; gg < 16; ++gg) s += part[i][gg][nn];
                short v = f2bf(s);
                int t = t0 + i;
                kvc16[t*16 + nn] = v;
                int b = t >> 11, tl = t & (TT-1);
                kvcT[(b*32 + nn)*TT + tl]      = v;
                kvcT[(b*32 + 16 + nn)*TT + tl] = 0;   // zero pad rows 16..31
            }
        }
        __syncthreads();   // smem reuse safety across items
    }

    grid_barrier(gen, flags, 1u);

    // ================= phase 1: q' GEMM =================
    for (int t = bid; t < 1024; t += NBLK) {
        int w = tid >> 6, lane = tid & 63;
        int l15 = lane & 15, g = lane >> 4;
        int m0 = (t >> 4)*64 + w*16;
        int nb = (t & 15)*16;
        f32x4 acc = {0.f,0.f,0.f,0.f};
        const short* arow = x_bf + (m0 + l15)*DM + 8*g;
        const short* brow = Wqt  + (nb + l15)*DM + 8*g;
        for (int k0 = 0; k0 < DM; k0 += 32) {
            short8 a = *(const short8*)(arow + k0);
            short8 b = *(const short8*)(brow + k0);
            acc = __builtin_amdgcn_mfma_f32_16x16x32_bf16(a, b, acc, 0, 0, 0);
        }
        int c = nb + l15;
        float bias = bqp[c];
        #pragma unroll
        for (int r = 0; r < 4; ++r) {
            int row = m0 + 4*g + r;
            q16[row*QP + c] = f2bf(acc[r] + bias);
        }
    }

    grid_barrier(gen, flags, 2u);

    // ================= phase 2: attention =================
    {
        float (*ulds)[32][17] = (float(*)[32][17])smem;      // 8704 B
        float (*dlds)[32]     = (float(*)[32])(smem + 8704); // 512 B
        int bh = bid & 31, pp = bid >> 5;      // pp in [0,16)
        int b = bh >> 4, h = bh & 15;
        int w = tid >> 6, lane = tid & 63;
        int l31 = lane & 31, hi = lane >> 5;

        // two complementary pairs: {pp, 63-pp} and {31-pp, 32+pp} -> 130 KV-tiles/block
        #pragma unroll 1
        for (int it = 0; it < 4; ++it) {
            int qt;
            switch (it) {
                case 0: qt = pp; break;
                case 1: qt = 63 - pp; break;
                case 2: qt = 31 - pp; break;
                default: qt = 32 + pp; break;
            }
            int qbase = qt * 32;

            short8 qf = *(const short8*)(q16 + (b*TT + qbase + l31)*QP + h*16 + 8*hi);
            const short* kbase = kvc16 + (b*TT + l31)*16 + 8*hi;
            const short* vrow  = kvcT + (b*32 + l31)*TT + 8*hi;

            int ntiles = qt + 1;
            int t0 = (w * ntiles) >> 2;
            int t1 = ((w + 1) * ntiles) >> 2;

            f32x16 u;
            f32x16 zf;
            #pragma unroll
            for (int r = 0; r < 16; ++r) { u[r] = 0.f; zf[r] = 0.f; }
            float lacc = 0.f;

            if (t0 < t1) {
                int kv0 = t0 << 5;
                short8 kf  = *(const short8*)(kbase + kv0*16);
                short8 va  = *(const short8*)(vrow + kv0);
                short8 vb  = *(const short8*)(vrow + kv0 + 16);
                for (int kt = t0; kt < t1; ++kt) {
                    short8 kf_n = kf, va_n = va, vb_n = vb;
                    if (kt + 1 < t1) {                  // prefetch next tile
                        int kvn = (kt + 1) << 5;
                        kf_n = *(const short8*)(kbase + kvn*16);
                        va_n = *(const short8*)(vrow + kvn);
                        vb_n = *(const short8*)(vrow + kvn + 16);
                    }
                    f32x16 st = __builtin_amdgcn_mfma_f32_32x32x16_bf16(kf, qf, zf, 0, 0, 0);
                    if (kt == qt) {                      // diagonal tile: mask kv > q
                        #pragma unroll
                        for (int r = 0; r < 16; ++r) {
                            int kvl = (r & 3) + 8*(r >> 2) + 4*hi;
                            if (kvl > l31) st[r] = -INFINITY;
                        }
                    }
                    float p[16];
                    #pragma unroll
                    for (int r = 0; r < 16; ++r) { p[r] = exp2f(st[r]); lacc += p[r]; }
                    int wd[8];
                    #pragma unroll
                    for (int i = 0; i < 8; ++i) {
                        asm("v_cvt_pk_bf16_f32 %0, %1, %2" : "=v"(wd[i]) : "v"(p[2*i]), "v"(p[2*i+1]));
                    }
                    // cross-half redistribute via permlane32_swap
                    int c00 = wd[0], c02 = wd[2], c01 = wd[1], c03 = wd[3];
                    int c10 = wd[4], c12 = wd[6], c11 = wd[5], c13 = wd[7];
                    asm volatile("v_permlane32_swap_b32 %0, %1" : "+v"(c00), "+v"(c02));
                    asm volatile("v_permlane32_swap_b32 %0, %1" : "+v"(c01), "+v"(c03));
                    asm volatile("v_permlane32_swap_b32 %0, %1" : "+v"(c10), "+v"(c12));
                    asm volatile("v_permlane32_swap_b32 %0, %1" : "+v"(c11), "+v"(c13));
                    union { int i4[4]; short8 s8; } pa0, pa1;
                    pa0.i4[0]=c00; pa0.i4[1]=c01; pa0.i4[2]=c02; pa0.i4[3]=c03;
                    pa1.i4[0]=c10; pa1.i4[1]=c11; pa1.i4[2]=c12; pa1.i4[3]=c13;
                    u = __builtin_amdgcn_mfma_f32_32x32x16_bf16(pa0.s8, va, u, 0, 0, 0);
                    u = __builtin_amdgcn_mfma_f32_32x32x16_bf16(pa1.s8, vb, u, 0, 0, 0);
                    kf = kf_n; va = va_n; vb = vb_n;
                }
            }

            // combine: per-wave partials are additive (no-max softmax)
            lacc += __shfl_xor(lacc, 32, 64);
            #pragma unroll
            for (int r = 0; r < 16; ++r) {
                int q = (r & 3) + 8*(r >> 2) + 4*hi;
                if (l31 < 16) ulds[w][q][l31] = u[r];
            }
            if (hi == 0) dlds[w][l31] = lacc;
            __syncthreads();
            #pragma unroll
            for (int e = 0; e < 2; ++e) {
                int idx = tid*2 + e;
                int q = idx >> 4, lat = idx & 15;
                float us = ulds[0][q][lat] + ulds[1][q][lat] + ulds[2][q][lat] + ulds[3][q][lat];
                float dd = dlds[0][q] + dlds[1][q] + dlds[2][q] + dlds[3][q];
                u_bf[(b*TT + qbase + q)*QP + h*16 + lat] = f2bf(us / dd);
            }
            __syncthreads();   // ulds/dlds reuse safety before next item
        }
    }

    grid_barrier(gen, flags, 3u);

    // ================= phase 3: output GEMM =================
    for (int t = bid; t < 1024; t += NBLK) {
        int w = tid >> 6, lane = tid & 63;
        int l15 = lane & 15, g = lane >> 4;
        int m0 = (t >> 4)*64 + w*16;
        int nb = (t & 15)*64;
        float* bs = (float*)smem;
        if (tid < 64) {
            int n = nb + tid;
            float s = bo[n];
            #pragma unroll
            for (int hh = 0; hh < 16; ++hh) s += bop_part[hh*DM + n];
            bs[tid] = s;
        }
        __syncthreads();
        f32x4 acc[4];
        #pragma unroll
        for (int nt = 0; nt < 4; ++nt) acc[nt] = (f32x4){0.f,0.f,0.f,0.f};
        const short* arow = u_bf + (m0 + l15)*QP + 8*g;
        for (int k0 = 0; k0 < QP; k0 += 32) {
            short8 a = *(const short8*)(arow + k0);
            #pragma unroll
            for (int nt = 0; nt < 4; ++nt) {
                short8 bfr = *(const short8*)(Wvot + (nb + nt*16 + l15)*QP + k0 + 8*g);
                acc[nt] = __builtin_amdgcn_mfma_f32_16x16x32_bf16(a, bfr, acc[nt], 0, 0, 0);
            }
        }
        #pragma unroll
        for (int nt = 0; nt < 4; ++nt) {
            int n = nb + nt*16 + l15;
            float bias = bs[nt*16 + l15];
            #pragma unroll
            for (int r = 0; r < 4; ++r)
                out[(m0 + 4*g + r)*DM + n] = acc[nt][r] + bias;
        }
        __syncthreads();   // bs reuse safety
    }
}

extern "C" void kernel_launch(void* const* d_in, const int* in_sizes, int n_in,
                              void* d_out, int out_size, void* d_ws, size_t ws_size,
                              hipStream_t stream) {
    const float* x  = (const float*)d_in[0];
    const float* Wc = (const float*)d_in[1];
    const float* bc = (const float*)d_in[2];
    const float* Wk = (const float*)d_in[3];
    // d_in[4] = bk: drops out of softmax (constant per row)
    const float* Wv = (const float*)d_in[5];
    const float* bv = (const float*)d_in[6];
    const float* Wq = (const float*)d_in[7];
    const float* bq = (const float*)d_in[8];
    const float* Wo = (const float*)d_in[9];
    const float* bo = (const float*)d_in[10];
    // d_in[11] = mask: causal, implemented directly
    float* out = (float*)d_out;

    char* ws = (char*)d_ws;                       // needs 16 MiB
    short* x_bf     = (short*)(ws);                              // 8 MiB
    short* Wqt      = (short*)(ws + (8u<<20));                   // 512 KiB
    short* Wvot     = (short*)(ws + (8u<<20) + (512u<<10));      // 512 KiB
    float* bqp      = (float*)(ws + (9u<<20));                   // 1 KiB
    float* bop_part = (float*)(ws + (9u<<20) + 8192);            // 64 KiB
    unsigned* bar   = (unsigned*)(ws + (9u<<20) + (128u<<10));   // 4 KiB barrier state
    short* kvc16    = (short*)(ws + (9u<<20) + (512u<<10));      // 128 KiB
    short* kvcT     = (short*)(ws + (9u<<20) + (768u<<10));      // 256 KiB [B][32][T]
    short* q16      = (short*)(ws + (10u<<20));                  // 2 MiB [BT][256]
    short* u_bf     = (short*)(ws + (14u<<20));                  // 2 MiB

    hipMemsetAsync(bar, 0, 4096, stream);   // zero barrier state (ws is poisoned)
    hipLaunchKernelGGL(mla_fused, dim3(NBLK), dim3(256), 0, stream,
                       Wq, Wk, bq, Wv, Wo, bv, x, Wc, bc, bo,
                       Wqt, bqp, Wvot, bop_part, x_bf, kvc16, kvcT,
                       q16, u_bf, out, bar);
}